// Round 17
// baseline (174.787 us; speedup 1.0000x reference)
//
#include <hip/hip_runtime.h>
#include <hip/hip_bf16.h>

// ---------------------------------------------------------------------------
// Decoder block on MI355X.
// R17: QKV GEMM (192 blocks) fused with W1/W2 weight transposes (64 blocks)
// in one 256-block launch -- the transposes run on the CUs the QKV grid
// leaves idle, hiding ~7us. GEMM core: R16 one-barrier 256x256/BK=64 with
// counted lgkm (best-passing). R11 traffic diet, wide reduce, heavy-first
// swapped-QK^T attention with defer-max.
// ---------------------------------------------------------------------------

typedef __attribute__((ext_vector_type(8))) short short8;
typedef __attribute__((ext_vector_type(4))) short short4v;
typedef __attribute__((ext_vector_type(4))) float f32x4;

#define DEVI static __device__ __forceinline__

#define BAR() __builtin_amdgcn_s_barrier()
#define SB0() __builtin_amdgcn_sched_barrier(0)

template <int N>
DEVI void vmwN() {
  asm volatile("s_waitcnt vmcnt(%0)" ::"n"(N) : "memory");
  __builtin_amdgcn_sched_barrier(0);
}
template <int N>
DEVI void lgkmN() {
  asm volatile("s_waitcnt lgkmcnt(%0)" ::"n"(N) : "memory");
  __builtin_amdgcn_sched_barrier(0);
}

DEVI void gload_lds16(const void* g, void* l) {
  __builtin_amdgcn_global_load_lds(
      (const __attribute__((address_space(1))) void*)g,
      (__attribute__((address_space(3))) void*)l, 16, 0, 0);
}

DEVI float bf2f(short s) {
  union { float f; unsigned u; } cv;
  cv.u = ((unsigned)(unsigned short)s) << 16;
  return cv.f;
}
DEVI short f2bf(float f) {  // round-to-nearest-even
  union { float f; unsigned u; } cv;
  cv.f = f;
  unsigned u = cv.u;
  u += 0x7FFFu + ((u >> 16) & 1u);
  return (short)(u >> 16);
}

DEVI void block_reduce2(float& s, float& s2, float* red, int t) {
#pragma unroll
  for (int off = 1; off < 64; off <<= 1) {
    s += __shfl_xor(s, off, 64);
    s2 += __shfl_xor(s2, off, 64);
  }
  __syncthreads();
  if ((t & 63) == 0) { red[(t >> 6) * 2] = s; red[(t >> 6) * 2 + 1] = s2; }
  __syncthreads();
  s = red[0] + red[2] + red[4] + red[6];
  s2 = red[1] + red[3] + red[5] + red[7];
}

// ---------------- qkv weight transpose (f32 -> bf16, 32x32) ----------------
__global__ __launch_bounds__(256) void transpose_qkvw(
    const float* __restrict__ Wq, const float* __restrict__ Wk,
    const float* __restrict__ Wv, short* __restrict__ wqkv_t) {
  __shared__ float tile[32][33];
  const int bid = blockIdx.x;  // 0..3071
  const int tx = threadIdx.x, ty = threadIdx.y;
  const int bx = bid & 1, rem = bid >> 1;
  const int by = rem & 31, z = rem >> 5;
  const int sel = z >> 4, b = z & 15;
  const float* in =
      ((sel == 0) ? Wq : (sel == 1) ? Wk : Wv) + (size_t)b * 1024 * 64;
  short* o = wqkv_t + (size_t)sel * 1024 * 1024 + (size_t)b * 1024 * 64;
  const int r0 = by * 32, c0 = bx * 32;
#pragma unroll
  for (int i = 0; i < 32; i += 8)
    tile[ty + i][tx] = in[(size_t)(r0 + ty + i) * 64 + c0 + tx];
  __syncthreads();
#pragma unroll
  for (int i = 0; i < 32; i += 8)
    o[(size_t)(c0 + ty + i) * 1024 + r0 + tx] = f2bf(tile[tx][ty + i]);
}

// ------------------------------- LayerNorms --------------------------------
__global__ __launch_bounds__(256) void ln1_kernel(
    const float* __restrict__ x, const float* __restrict__ g,
    const float* __restrict__ b, short* __restrict__ hb) {
  __shared__ float red[8];
  const int row = blockIdx.x, t = threadIdx.x;
  float4 v = ((const float4*)(x + (size_t)row * 1024))[t];
  float s = v.x + v.y + v.z + v.w;
  float s2 = v.x * v.x + v.y * v.y + v.z * v.z + v.w * v.w;
  block_reduce2(s, s2, red, t);
  const float mu = s * (1.0f / 1024.0f);
  const float rstd = rsqrtf(s2 * (1.0f / 1024.0f) - mu * mu + 1e-5f);
  float4 gv = ((const float4*)g)[t], bv = ((const float4*)b)[t];
  short4v p = {f2bf((v.x - mu) * rstd * gv.x + bv.x),
               f2bf((v.y - mu) * rstd * gv.y + bv.y),
               f2bf((v.z - mu) * rstd * gv.z + bv.z),
               f2bf((v.w - mu) * rstd * gv.w + bv.w)};
  ((short4v*)(hb + (size_t)row * 1024))[t] = p;
}

__global__ __launch_bounds__(256) void ln2f_kernel(
    const short* __restrict__ hbb, const short* __restrict__ ob,
    const float* __restrict__ g2, const float* __restrict__ b2,
    const float* __restrict__ gf, const float* __restrict__ bfp,
    short* __restrict__ x3, short* __restrict__ hfb) {
  __shared__ float red[8];
  const int row = blockIdx.x, t = threadIdx.x;
  short4v hv4 = ((const short4v*)(hbb + (size_t)row * 1024))[t];
  short4v ov4 = ((const short4v*)(ob + (size_t)row * 1024))[t];
  float4 v;
  v.x = bf2f(hv4.x) + bf2f(ov4.x);
  v.y = bf2f(hv4.y) + bf2f(ov4.y);
  v.z = bf2f(hv4.z) + bf2f(ov4.z);
  v.w = bf2f(hv4.w) + bf2f(ov4.w);
  float s = v.x + v.y + v.z + v.w;
  float s2 = v.x * v.x + v.y * v.y + v.z * v.z + v.w * v.w;
  block_reduce2(s, s2, red, t);
  float mu = s * (1.0f / 1024.0f);
  float rstd = rsqrtf(s2 * (1.0f / 1024.0f) - mu * mu + 1e-5f);
  float4 gv = ((const float4*)g2)[t], bv = ((const float4*)b2)[t];
  float4 xv;
  xv.x = (v.x - mu) * rstd * gv.x + bv.x;
  xv.y = (v.y - mu) * rstd * gv.y + bv.y;
  xv.z = (v.z - mu) * rstd * gv.z + bv.z;
  xv.w = (v.w - mu) * rstd * gv.w + bv.w;
  short4v xp = {f2bf(xv.x), f2bf(xv.y), f2bf(xv.z), f2bf(xv.w)};
  ((short4v*)(x3 + (size_t)row * 1024))[t] = xp;
  s = xv.x + xv.y + xv.z + xv.w;
  s2 = xv.x * xv.x + xv.y * xv.y + xv.z * xv.z + xv.w * xv.w;
  block_reduce2(s, s2, red, t);
  mu = s * (1.0f / 1024.0f);
  rstd = rsqrtf(s2 * (1.0f / 1024.0f) - mu * mu + 1e-5f);
  float4 gv2 = ((const float4*)gf)[t], bv2 = ((const float4*)bfp)[t];
  short4v pk = {f2bf((xv.x - mu) * rstd * gv2.x + bv2.x),
                f2bf((xv.y - mu) * rstd * gv2.y + bv2.y),
                f2bf((xv.z - mu) * rstd * gv2.z + bv2.z),
                f2bf((xv.w - mu) * rstd * gv2.w + bv2.w)};
  ((short4v*)(hfb + (size_t)row * 1024))[t] = pk;
}

// -------- 256x256 GEMM core, ONE barrier per K-tile, counted lgkm ----------
template <int EPI>
DEVI void gemm8_body(const short* __restrict__ A, const short* __restrict__ B,
                     int K, int kbase, int m0, int n0,
                     const float* __restrict__ f0, const float* __restrict__ f1,
                     const float* __restrict__ f2, short* __restrict__ s0,
                     short* __restrict__ s1, short* __restrict__ s2) {
  extern __shared__ __align__(16) char lds[];  // 131072 B
  constexpr int NT = 16;
  const int tid = threadIdx.x;
  const int l = tid & 63, w = tid >> 6;
  const int wrM = w >> 2, wcN = w & 3;
  const int lr = l & 15, lg = l >> 4;

  const int cswz = (((lr & 1) << 2) | lg) ^ (lr >> 1);
  const int laneoff = ((lr >> 1) << 7) + (cswz << 4);

  const int rsel = l >> 3;
  const int scz = (l & 7) ^ rsel;
  const int s_roff = w * 16 + rsel * 2 + (scz >> 2);
  const int s_kc = (scz & 3) * 8;
  const short* Asrc = A + (size_t)(m0 + s_roff) * K + kbase + s_kc;
  const short* Bsrc = B + (size_t)(n0 + s_roff) * K + kbase + s_kc;
  const size_t rstep = (size_t)128 * K;

  auto STAGE = [&](int op, int kh, int t) {
    const short* g = (op ? Bsrc : Asrc) + t * 64 + kh * 32;
    char* d = lds + ((t & 1) * 65536 + op * 32768 + kh * 16384 + w * 1024);
    gload_lds16(g, d);
    gload_lds16(g + rstep, d + 8192);
  };

  f32x4 acc[8][4] = {};

  STAGE(0, 0, 0); STAGE(1, 0, 0); STAGE(0, 1, 0); STAGE(1, 1, 0);
  vmwN<0>(); BAR(); SB0();

  for (int t = 0; t < NT; ++t) {
    const bool st = (t + 1) < NT;
    const char* pa0 = lds + (t & 1) * 65536 + wrM * 8192 + laneoff;
    const char* pb0 = lds + (t & 1) * 65536 + 32768 + wcN * 4096 + laneoff;
#pragma unroll
    for (int kh = 0; kh < 2; ++kh) {
      const char* pa = pa0 + kh * 16384;
      const char* pb = pb0 + kh * 16384;
      short8 a[8], b[4];
#pragma unroll
      for (int mt = 0; mt < 8; ++mt) a[mt] = *(const short8*)(pa + mt * 1024);
      b[0] = *(const short8*)(pb);
      b[1] = *(const short8*)(pb + 1024);
      SB0();
      b[2] = *(const short8*)(pb + 2048);
      b[3] = *(const short8*)(pb + 3072);
      if (kh == 0 && st) {
        STAGE(0, 0, t + 1); STAGE(1, 0, t + 1);
        STAGE(0, 1, t + 1); STAGE(1, 1, t + 1);
      }
      lgkmN<2>();
      __builtin_amdgcn_s_setprio(1);
#pragma unroll
      for (int mt = 0; mt < 8; ++mt) {
        acc[mt][0] = __builtin_amdgcn_mfma_f32_16x16x32_bf16(a[mt], b[0], acc[mt][0], 0, 0, 0);
        acc[mt][1] = __builtin_amdgcn_mfma_f32_16x16x32_bf16(a[mt], b[1], acc[mt][1], 0, 0, 0);
      }
      __builtin_amdgcn_s_setprio(0);
      lgkmN<0>();
      __builtin_amdgcn_s_setprio(1);
#pragma unroll
      for (int mt = 0; mt < 8; ++mt) {
        acc[mt][2] = __builtin_amdgcn_mfma_f32_16x16x32_bf16(a[mt], b[2], acc[mt][2], 0, 0, 0);
        acc[mt][3] = __builtin_amdgcn_mfma_f32_16x16x32_bf16(a[mt], b[3], acc[mt][3], 0, 0, 0);
      }
      __builtin_amdgcn_s_setprio(0);
    }
    if (st) vmwN<0>();
    BAR(); SB0();
  }

  // --------------------------- epilogue ---------------------------
#pragma unroll
  for (int mt = 0; mt < 8; ++mt) {
#pragma unroll
    for (int nt = 0; nt < 4; ++nt) {
      const int col = n0 + wcN * 64 + nt * 16 + lr;
      const int row0 = m0 + wrM * 128 + mt * 16 + lg * 4;
      if constexpr (EPI == 0) {  // QKV scatter
        const int sel = col >> 10, nn = col & 1023;
        const int hh = nn >> 6, dd = nn & 63;
        const int bb = row0 >> 10, tt0 = row0 & 1023;
        if (sel == 2) {
          const float bias = f2[nn];
          short4v pk = {f2bf(acc[mt][nt][0] + bias), f2bf(acc[mt][nt][1] + bias),
                        f2bf(acc[mt][nt][2] + bias), f2bf(acc[mt][nt][3] + bias)};
          *(short4v*)&s2[(((size_t)(bb * 16 + hh)) * 64 + dd) * 1024 + tt0] = pk;
        } else {
          const float bias = (sel == 0) ? f0[nn] : f1[nn];
          short* dst = (sel == 0) ? s0 : s1;
#pragma unroll
          for (int r = 0; r < 4; ++r)
            dst[(((size_t)(bb * 16 + hh)) * 1024 + tt0 + r) * 64 + dd] =
                f2bf(acc[mt][nt][r] + bias);
        }
      } else if constexpr (EPI == 1) {  // FFN1 bias+relu -> bf16
#pragma unroll
        for (int r = 0; r < 4; ++r) {
          float val = fmaxf(acc[mt][nt][r] + f0[col], 0.0f);
          s0[(size_t)(row0 + r) * 4096 + col] = f2bf(val);
        }
      } else {  // split-K partials, bf16
#pragma unroll
        for (int r = 0; r < 4; ++r)
          s0[(size_t)(row0 + r) * 1024 + col] = f2bf(acc[mt][nt][r]);
      }
    }
  }
}

// ---- QKV GEMM (blocks 0..191) fused with W1/W2 transposes (192..255) ------
__global__ __launch_bounds__(512, 1) void gemm8_qkv_fused(
    const short* __restrict__ A, const short* __restrict__ B,
    const float* __restrict__ bq, const float* __restrict__ bk,
    const float* __restrict__ bv, short* __restrict__ q,
    short* __restrict__ k, short* __restrict__ vt,
    const float* __restrict__ W1, const float* __restrict__ W2,
    short* __restrict__ w1_t, short* __restrict__ w2_t) {
  const int flat = blockIdx.y * 16 + blockIdx.x;  // grid (16,16) = 256
  if (flat < 192) {
    // bijective XCD swizzle within the 192 GEMM blocks (192 % 8 == 0)
    const int nf = (flat & 7) * 24 + (flat >> 3);
    const int bx = nf % 12, by = nf / 12;
    gemm8_body<0>(A, B, 1024, 0, by * 256, bx * 256, bq, bk, bv, q, k, vt);
    return;
  }
  // ---- transpose W1 [1024][4096] -> w1_t, W2 [4096][1024] -> w2_t ----
  // 8192 32x32 tiles; 64 blocks x 2 units x 64 iters. Units share the
  // 512-thread __syncthreads (loop counts identical across units).
  extern __shared__ __align__(16) char lds[];
  const int tid = threadIdx.x;
  const int unit = tid >> 8, lt = tid & 255;
  const int tx = lt & 31, ty = lt >> 5;  // 32 x 8
  float* tile = (float*)lds + unit * (32 * 33);
  const int base = (flat - 192) * 2 + unit;  // 0..127
  for (int it = 0; it < 64; ++it) {
    const int tix = base + it * 128;  // 0..8191
    const float* in; short* o; int R, C, bx, by;
    if (tix < 4096) { in = W1; o = w1_t; R = 1024; C = 4096; bx = tix & 127; by = tix >> 7; }
    else { const int t2 = tix - 4096; in = W2; o = w2_t; R = 4096; C = 1024; bx = t2 & 31; by = t2 >> 5; }
    const int r0 = by * 32, c0 = bx * 32;
#pragma unroll
    for (int i = 0; i < 32; i += 8)
      tile[(ty + i) * 33 + tx] = in[(size_t)(r0 + ty + i) * C + c0 + tx];
    __syncthreads();
#pragma unroll
    for (int i = 0; i < 32; i += 8)
      o[(size_t)(c0 + ty + i) * R + r0 + tx] = f2bf(tile[tx * 33 + ty + i]);
    __syncthreads();
  }
}

__global__ __launch_bounds__(512, 2) void gemm8_ffn1(
    const short* __restrict__ A, const short* __restrict__ B,
    const float* __restrict__ b1f, short* __restrict__ u) {
  const int flat = blockIdx.y * 16 + blockIdx.x;
  const int nf = (flat & 7) * 32 + (flat >> 3);
  const int bx = nf & 15, by = nf >> 4;
  gemm8_body<1>(A, B, 1024, 0, by * 256, bx * 256, b1f, nullptr, nullptr, u,
                nullptr, nullptr);
}

// split-K x4: z in [0,4), K-chunk of 1024 over K=4096; writes bf16 partials.
__global__ __launch_bounds__(512, 2) void gemm8_ffn2sk(
    const short* __restrict__ A, const short* __restrict__ B,
    short* __restrict__ part) {
  const int z = blockIdx.z;
  const int flat = blockIdx.y * 4 + blockIdx.x;
  const int nf = (flat & 7) * 8 + (flat >> 3);
  const int bx = nf & 3, by = nf >> 2;
  gemm8_body<2>(A, B, 4096, z * 1024, by * 256, bx * 256, nullptr, nullptr,
                nullptr, part + (size_t)z * 4096 * 1024, nullptr, nullptr);
}

// out = sum_z part[z] + b2f + hf + x3  (partials/hf/x3 bf16, out f32)
__global__ __launch_bounds__(256) void ffn2_reduce(
    const short* __restrict__ part, const float* __restrict__ b2f,
    const short* __restrict__ hfb, const short* __restrict__ x3,
    float* __restrict__ out) {
  const size_t i8 = (size_t)blockIdx.x * 256 + threadIdx.x;  // short8 index
  const size_t S = (size_t)4096 * 1024 / 8;
  short8 a0 = ((const short8*)part)[i8];
  short8 a1 = ((const short8*)part)[i8 + S];
  short8 a2 = ((const short8*)part)[i8 + 2 * S];
  short8 a3 = ((const short8*)part)[i8 + 3 * S];
  short8 xv = ((const short8*)x3)[i8];
  short8 hv = ((const short8*)hfb)[i8];
  const int cb = (int)((i8 * 2) & 255);
  float4 bb0 = ((const float4*)b2f)[cb];
  float4 bb1 = ((const float4*)b2f)[cb + 1];
  float ob[8];
#pragma unroll
  for (int j = 0; j < 8; ++j) {
    const float bbv = j < 4 ? ((const float*)&bb0)[j] : ((const float*)&bb1)[j - 4];
    ob[j] = bf2f(a0[j]) + bf2f(a1[j]) + bf2f(a2[j]) + bf2f(a3[j]) + bbv +
            bf2f(hv[j]) + bf2f(xv[j]);
  }
  float4 o0 = {ob[0], ob[1], ob[2], ob[3]};
  float4 o1 = {ob[4], ob[5], ob[6], ob[7]};
  ((float4*)out)[i8 * 2] = o0;
  ((float4*)out)[i8 * 2 + 1] = o1;
}

// ----------------------------- flash attention -----------------------------
__global__ __launch_bounds__(256, 5) void attn_kernel(
    const short* __restrict__ q, const short* __restrict__ k,
    const short* __restrict__ vt, short* __restrict__ o) {
  __shared__ __align__(16) short Ksm[64 * 64];
  __shared__ __align__(16) short Vsm[64 * 64];
  __shared__ __align__(16) short Psm[4 * 16 * 64];
  const int bh = blockIdx.x;
  const int qt = 15 - blockIdx.y;  // heavy blocks dispatch FIRST
  const int tid = threadIdx.x, lane = tid & 63, w = tid >> 6;
  const int lr = lane & 15, lg = lane >> 4;

  const short* qb = q + (size_t)bh * 1024 * 64;
  const short* kb = k + (size_t)bh * 1024 * 64;
  const short* vb = vt + (size_t)bh * 64 * 1024;

  const int qrow = qt * 64 + w * 16 + lr;
  short8 qf0 = *(const short8*)&qb[(size_t)qrow * 64 + lg * 8];
  short8 qf1 = *(const short8*)&qb[(size_t)qrow * 64 + 32 + lg * 8];

  f32x4 oacc[4] = {};
  float mrun = -1e30f, lrun = 0.0f;

  const float scale2 = 0.03125f * 1.44269504088896f;  // (1/sqrt(C))*log2(e)
  const int srow = tid >> 3;
  const int sc8 = tid & 7;
  char* pw = (char*)(Psm + w * 1024);
  const int qloc = w * 16 + lr;
  const int rowswz = (lr & 7) << 4;

  short8 kreg[2], vreg[2];
#pragma unroll
  for (int p = 0; p < 2; ++p) {
    const int rr = srow + p * 32;
    kreg[p] = *(const short8*)&kb[(size_t)rr * 64 + sc8 * 8];
    vreg[p] = *(const short8*)&vb[(size_t)rr * 1024 + sc8 * 8];
  }

  for (int kt = 0; kt <= qt; ++kt) {
#pragma unroll
    for (int p = 0; p < 2; ++p) {
      const int rr = srow + p * 32;
      *(short8*)((char*)Ksm + rr * 128 + ((sc8 ^ (rr & 7)) << 4)) = kreg[p];
      *(short8*)((char*)Vsm + rr * 128 + ((sc8 ^ (rr & 7)) << 4)) = vreg[p];
    }
    __syncthreads();
    if (kt < qt) {
#pragma unroll
      for (int p = 0; p < 2; ++p) {
        const int rr = srow + p * 32;
        kreg[p] =
            *(const short8*)&kb[((size_t)((kt + 1) * 64 + rr)) * 64 + sc8 * 8];
        vreg[p] =
            *(const short8*)&vb[(size_t)rr * 1024 + (kt + 1) * 64 + sc8 * 8];
      }
    }

    f32x4 sfr[4];
#pragma unroll
    for (int nt = 0; nt < 4; ++nt) {
      const int krow = nt * 16 + lr;
      short8 kf0 = *(const short8*)((const char*)Ksm + krow * 128 +
                                    (((0 + lg) ^ (krow & 7)) << 4));
      short8 kf1 = *(const short8*)((const char*)Ksm + krow * 128 +
                                    (((4 + lg) ^ (krow & 7)) << 4));
      f32x4 z = {};
      z = __builtin_amdgcn_mfma_f32_16x16x32_bf16(kf0, qf0, z, 0, 0, 0);
      z = __builtin_amdgcn_mfma_f32_16x16x32_bf16(kf1, qf1, z, 0, 0, 0);
      sfr[nt] = z;
    }
    if (kt == qt) {
#pragma unroll
      for (int nt = 0; nt < 4; ++nt) {
        const int kb0 = nt * 16 + lg * 4;
#pragma unroll
        for (int r = 0; r < 4; ++r)
          sfr[nt][r] = (kb0 + r <= qloc) ? sfr[nt][r] * scale2 : -1e30f;
      }
    } else {
#pragma unroll
      for (int nt = 0; nt < 4; ++nt)
#pragma unroll
        for (int r = 0; r < 4; ++r) sfr[nt][r] *= scale2;
    }
    float pm;
    {
      float a0 = fmaxf(fmaxf(sfr[0][0], sfr[0][1]), fmaxf(sfr[0][2], sfr[0][3]));
      float a1 = fmaxf(fmaxf(sfr[1][0], sfr[1][1]), fmaxf(sfr[1][2], sfr[1][3]));
      float a2 = fmaxf(fmaxf(sfr[2][0], sfr[2][1]), fmaxf(sfr[2][2], sfr[2][3]));
      float a3 = fmaxf(fmaxf(sfr[3][0], sfr[3][1]), fmaxf(sfr[3][2], sfr[3][3]));
      pm = fmaxf(fmaxf(a0, a1), fmaxf(a2, a3));
      pm = fmaxf(pm, __shfl_xor(pm, 16, 64));
      pm = fmaxf(pm, __shfl_xor(pm, 32, 64));
    }
    if (!__all(pm - mrun <= 8.0f)) {
      const float mnew = fmaxf(mrun, pm);
      const float alpha = exp2f(mrun - mnew);
      mrun = mnew;
      lrun *= alpha;
#pragma unroll
      for (int nt = 0; nt < 4; ++nt)
#pragma unroll
        for (int r = 0; r < 4; ++r) oacc[nt][r] *= alpha;
    }
    float rs;
    {
#pragma unroll
      for (int nt = 0; nt < 4; ++nt)
#pragma unroll
        for (int r = 0; r < 4; ++r) sfr[nt][r] = exp2f(sfr[nt][r] - mrun);
      float s0 = (sfr[0][0] + sfr[0][1]) + (sfr[0][2] + sfr[0][3]);
      float s1 = (sfr[1][0] + sfr[1][1]) + (sfr[1][2] + sfr[1][3]);
      float s2 = (sfr[2][0] + sfr[2][1]) + (sfr[2][2] + sfr[2][3]);
      float s3 = (sfr[3][0] + sfr[3][1]) + (sfr[3][2] + sfr[3][3]);
      rs = (s0 + s1) + (s2 + s3);
      rs += __shfl_xor(rs, 16, 64);
      rs += __shfl_xor(rs, 32, 64);
    }
    lrun += rs;

#pragma unroll
    for (int nt = 0; nt < 4; ++nt) {
      unsigned w0, w1;
      asm("v_cvt_pk_bf16_f32 %0, %1, %2"
          : "=v"(w0) : "v"(sfr[nt][0]), "v"(sfr[nt][1]));
      asm("v_cvt_pk_bf16_f32 %0, %1, %2"
          : "=v"(w1) : "v"(sfr[nt][2]), "v"(sfr[nt][3]));
      uint2 pk2 = {w0, w1};
      *(uint2*)(pw + lr * 128 + ((nt * 32 + lg * 8) ^ rowswz)) = pk2;
    }

#pragma unroll
    for (int kc = 0; kc < 2; ++kc) {
      short8 pb8 = *(const short8*)(pw + lr * 128 + ((kc * 64 + lg * 16) ^ rowswz));
#pragma unroll
      for (int nt = 0; nt < 4; ++nt) {
        const int vrow = nt * 16 + lr;
        short8 vf = *(const short8*)((const char*)Vsm + vrow * 128 +
                                     (((kc * 4 + lg) ^ (vrow & 7)) << 4));
        oacc[nt] = __builtin_amdgcn_mfma_f32_16x16x32_bf16(vf, pb8, oacc[nt], 0, 0, 0);
      }
    }
    __syncthreads();
  }

  const float inv = 1.0f / lrun;
  short* ob = o + (size_t)(bh >> 4) * 1024 * 1024 +
              (size_t)(qt * 64 + qloc) * 1024 + (bh & 15) * 64;
#pragma unroll
  for (int nt = 0; nt < 4; ++nt) {
    short4v pk = {f2bf(oacc[nt][0] * inv), f2bf(oacc[nt][1] * inv),
                  f2bf(oacc[nt][2] * inv), f2bf(oacc[nt][3] * inv)};
    *(short4v*)&ob[nt * 16 + lg * 4] = pk;
  }
}

// ------------------------------- launcher ----------------------------------
extern "C" void kernel_launch(void* const* d_in, const int* in_sizes, int n_in,
                              void* d_out, int out_size, void* d_ws,
                              size_t ws_size, hipStream_t stream) {
  const float* x = (const float*)d_in[0];
  const float* Wq = (const float*)d_in[1];
  const float* bq = (const float*)d_in[2];
  const float* Wk = (const float*)d_in[3];
  const float* bk = (const float*)d_in[4];
  const float* Wv = (const float*)d_in[5];
  const float* bv = (const float*)d_in[6];
  const float* g1 = (const float*)d_in[7];
  const float* b1 = (const float*)d_in[8];
  const float* g2 = (const float*)d_in[9];
  const float* b2 = (const float*)d_in[10];
  const float* gf = (const float*)d_in[11];
  const float* bfp = (const float*)d_in[12];
  const float* W1 = (const float*)d_in[13];
  const float* b1f = (const float*)d_in[14];
  const float* W2 = (const float*)d_in[15];
  const float* b2f = (const float*)d_in[16];
  float* out = (float*)d_out;

  (void)hipFuncSetAttribute((const void*)gemm8_qkv_fused,
                            hipFuncAttributeMaxDynamicSharedMemorySize, 131072);
  (void)hipFuncSetAttribute((const void*)gemm8_ffn1,
                            hipFuncAttributeMaxDynamicSharedMemorySize, 131072);
  (void)hipFuncSetAttribute((const void*)gemm8_ffn2sk,
                            hipFuncAttributeMaxDynamicSharedMemorySize, 131072);

  const size_t MB = 1024 * 1024;
  char* p = (char*)d_ws;
  // Region A (48MB): all dead before gemm8_ffn2sk; 32MB bf16 partials alias.
  short* qbuf = (short*)(p + 0 * MB);      // 8MB  dead after attn
  short* kbuf = (short*)(p + 8 * MB);      // 8MB  dead after attn
  short* vtb = (short*)(p + 16 * MB);      // 8MB  dead after attn
  short* obuf = (short*)(p + 24 * MB);     // 8MB  bf16 O, dead after ln2f
  short* wqkv_t = (short*)(p + 32 * MB);   // 6MB  dead after gemm8_qkv
  short* w1_t = (short*)(p + 40 * MB);     // 8MB  dead after gemm8_ffn1
  short* part = (short*)(p + 0 * MB);      // 32MB bf16 partials (alias)
  // Region B (64MB): live through the end.
  char* q = p + 48 * MB;
  short* w2_t = (short*)(q + 0 * MB);      // 8MB
  short* hbb = (short*)(q + 8 * MB);       // 8MB
  short* x3b = (short*)(q + 16 * MB);      // 8MB bf16
  short* hfb = (short*)(q + 24 * MB);      // 8MB
  short* ub = (short*)(q + 32 * MB);       // 32MB

  transpose_qkvw<<<3072, dim3(32, 8), 0, stream>>>(Wq, Wk, Wv, wqkv_t);

  ln1_kernel<<<4096, 256, 0, stream>>>(x, g1, b1, hbb);

  gemm8_qkv_fused<<<dim3(16, 16), 512, 131072, stream>>>(
      hbb, wqkv_t, bq, bk, bv, qbuf, kbuf, vtb, W1, W2, w1_t, w2_t);

  attn_kernel<<<dim3(64, 16), 256, 0, stream>>>(qbuf, kbuf, vtb, obuf);

  ln2f_kernel<<<4096, 256, 0, stream>>>(hbb, obuf, g2, b2, gf, bfp, x3b, hfb);

  gemm8_ffn1<<<dim3(16, 16), 512, 131072, stream>>>(hfb, w1_t, b1f, ub);

  gemm8_ffn2sk<<<dim3(4, 16, 4), 512, 131072, stream>>>(ub, w2_t, part);

  ffn2_reduce<<<2048, 256, 0, stream>>>(part, b2f, hfb, x3b, out);
}

// Round 18
// 172.486 us; speedup vs baseline: 1.0133x; 1.0133x over previous
//
#include <hip/hip_runtime.h>
#include <hip/hip_bf16.h>

// ---------------------------------------------------------------------------
// Decoder block on MI355X.  (R18 = R16 restored: best-measured configuration)
// GEMM core: 256x256 / BK=64 / 8-wave, ONE barrier per K-tile, counted lgkm.
// Per tile t: reads kh0 (10+2 split by SB0) | STAGE all 4 units of t+1 |
// lgkm(2) MFMA01 | lgkm(0) MFMA23 | reads kh1 (same) | VMW(0) | BAR.
// R11 traffic diet (bf16 intermediates), R13 fused transposes + wide reduce,
// R14 BM=256 all GEMMs. Attention: swapped-QK^T flash + heavy-first +
// defer-max.
// ---------------------------------------------------------------------------

typedef __attribute__((ext_vector_type(8))) short short8;
typedef __attribute__((ext_vector_type(4))) short short4v;
typedef __attribute__((ext_vector_type(4))) float f32x4;

#define DEVI static __device__ __forceinline__

#define BAR() __builtin_amdgcn_s_barrier()
#define SB0() __builtin_amdgcn_sched_barrier(0)

template <int N>
DEVI void vmwN() {
  asm volatile("s_waitcnt vmcnt(%0)" ::"n"(N) : "memory");
  __builtin_amdgcn_sched_barrier(0);
}
template <int N>
DEVI void lgkmN() {
  asm volatile("s_waitcnt lgkmcnt(%0)" ::"n"(N) : "memory");
  __builtin_amdgcn_sched_barrier(0);
}

DEVI void gload_lds16(const void* g, void* l) {
  __builtin_amdgcn_global_load_lds(
      (const __attribute__((address_space(1))) void*)g,
      (__attribute__((address_space(3))) void*)l, 16, 0, 0);
}

DEVI float bf2f(short s) {
  union { float f; unsigned u; } cv;
  cv.u = ((unsigned)(unsigned short)s) << 16;
  return cv.f;
}
DEVI short f2bf(float f) {  // round-to-nearest-even
  union { float f; unsigned u; } cv;
  cv.f = f;
  unsigned u = cv.u;
  u += 0x7FFFu + ((u >> 16) & 1u);
  return (short)(u >> 16);
}

DEVI void block_reduce2(float& s, float& s2, float* red, int t) {
#pragma unroll
  for (int off = 1; off < 64; off <<= 1) {
    s += __shfl_xor(s, off, 64);
    s2 += __shfl_xor(s2, off, 64);
  }
  __syncthreads();
  if ((t & 63) == 0) { red[(t >> 6) * 2] = s; red[(t >> 6) * 2 + 1] = s2; }
  __syncthreads();
  s = red[0] + red[2] + red[4] + red[6];
  s2 = red[1] + red[3] + red[5] + red[7];
}

// bijective XCD swizzle: nwg must be divisible by 8 (all our GEMM grids are).
DEVI void xcd_swz(int gx, int gy, int& bx, int& by) {
  const int flat = blockIdx.y * gx + blockIdx.x;
  const int c = (gx * gy) >> 3;
  const int nf = (flat & 7) * c + (flat >> 3);
  bx = nf % gx;
  by = nf / gx;
}

// ------------- fused weight transposes (f32 -> bf16, 32x32 tiles) ----------
__global__ __launch_bounds__(256) void transpose_all(
    const float* __restrict__ Wq, const float* __restrict__ Wk,
    const float* __restrict__ Wv, const float* __restrict__ W1,
    const float* __restrict__ W2, short* __restrict__ wqkv_t,
    short* __restrict__ w1_t, short* __restrict__ w2_t) {
  __shared__ float tile[32][33];
  const int bid = blockIdx.x;
  const int tx = threadIdx.x, ty = threadIdx.y;
  const float* in;
  short* o;
  int r0, c0, R, C;
  if (bid < 3072) {  // qkv: (x=2, y=32, z=48)
    const int bx = bid & 1, rem = bid >> 1;
    const int by = rem & 31, z = rem >> 5;
    const int sel = z >> 4, b = z & 15;
    in = ((sel == 0) ? Wq : (sel == 1) ? Wk : Wv) + (size_t)b * 1024 * 64;
    o = wqkv_t + (size_t)sel * 1024 * 1024 + (size_t)b * 1024 * 64;
    r0 = by * 32; c0 = bx * 32; R = 1024; C = 64;
  } else if (bid < 7168) {  // W1: (x=128, y=32)
    const int b2 = bid - 3072;
    const int bx = b2 & 127, by = b2 >> 7;
    in = W1; o = w1_t;
    r0 = by * 32; c0 = bx * 32; R = 1024; C = 4096;
  } else {  // W2: (x=32, y=128)
    const int b2 = bid - 7168;
    const int bx = b2 & 31, by = b2 >> 5;
    in = W2; o = w2_t;
    r0 = by * 32; c0 = bx * 32; R = 4096; C = 1024;
  }
#pragma unroll
  for (int i = 0; i < 32; i += 8)
    tile[ty + i][tx] = in[(size_t)(r0 + ty + i) * C + c0 + tx];
  __syncthreads();
#pragma unroll
  for (int i = 0; i < 32; i += 8)
    o[(size_t)(c0 + ty + i) * R + r0 + tx] = f2bf(tile[tx][ty + i]);
}

// ------------------------------- LayerNorms --------------------------------
__global__ __launch_bounds__(256) void ln1_kernel(
    const float* __restrict__ x, const float* __restrict__ g,
    const float* __restrict__ b, short* __restrict__ hb) {
  __shared__ float red[8];
  const int row = blockIdx.x, t = threadIdx.x;
  float4 v = ((const float4*)(x + (size_t)row * 1024))[t];
  float s = v.x + v.y + v.z + v.w;
  float s2 = v.x * v.x + v.y * v.y + v.z * v.z + v.w * v.w;
  block_reduce2(s, s2, red, t);
  const float mu = s * (1.0f / 1024.0f);
  const float rstd = rsqrtf(s2 * (1.0f / 1024.0f) - mu * mu + 1e-5f);
  float4 gv = ((const float4*)g)[t], bv = ((const float4*)b)[t];
  short4v p = {f2bf((v.x - mu) * rstd * gv.x + bv.x),
               f2bf((v.y - mu) * rstd * gv.y + bv.y),
               f2bf((v.z - mu) * rstd * gv.z + bv.z),
               f2bf((v.w - mu) * rstd * gv.w + bv.w)};
  ((short4v*)(hb + (size_t)row * 1024))[t] = p;
}

__global__ __launch_bounds__(256) void ln2f_kernel(
    const short* __restrict__ hbb, const short* __restrict__ ob,
    const float* __restrict__ g2, const float* __restrict__ b2,
    const float* __restrict__ gf, const float* __restrict__ bfp,
    short* __restrict__ x3, short* __restrict__ hfb) {
  __shared__ float red[8];
  const int row = blockIdx.x, t = threadIdx.x;
  short4v hv4 = ((const short4v*)(hbb + (size_t)row * 1024))[t];
  short4v ov4 = ((const short4v*)(ob + (size_t)row * 1024))[t];
  float4 v;
  v.x = bf2f(hv4.x) + bf2f(ov4.x);
  v.y = bf2f(hv4.y) + bf2f(ov4.y);
  v.z = bf2f(hv4.z) + bf2f(ov4.z);
  v.w = bf2f(hv4.w) + bf2f(ov4.w);
  float s = v.x + v.y + v.z + v.w;
  float s2 = v.x * v.x + v.y * v.y + v.z * v.z + v.w * v.w;
  block_reduce2(s, s2, red, t);
  float mu = s * (1.0f / 1024.0f);
  float rstd = rsqrtf(s2 * (1.0f / 1024.0f) - mu * mu + 1e-5f);
  float4 gv = ((const float4*)g2)[t], bv = ((const float4*)b2)[t];
  float4 xv;
  xv.x = (v.x - mu) * rstd * gv.x + bv.x;
  xv.y = (v.y - mu) * rstd * gv.y + bv.y;
  xv.z = (v.z - mu) * rstd * gv.z + bv.z;
  xv.w = (v.w - mu) * rstd * gv.w + bv.w;
  short4v xp = {f2bf(xv.x), f2bf(xv.y), f2bf(xv.z), f2bf(xv.w)};
  ((short4v*)(x3 + (size_t)row * 1024))[t] = xp;
  s = xv.x + xv.y + xv.z + xv.w;
  s2 = xv.x * xv.x + xv.y * xv.y + xv.z * xv.z + xv.w * xv.w;
  block_reduce2(s, s2, red, t);
  mu = s * (1.0f / 1024.0f);
  rstd = rsqrtf(s2 * (1.0f / 1024.0f) - mu * mu + 1e-5f);
  float4 gv2 = ((const float4*)gf)[t], bv2 = ((const float4*)bfp)[t];
  short4v pk = {f2bf((xv.x - mu) * rstd * gv2.x + bv2.x),
                f2bf((xv.y - mu) * rstd * gv2.y + bv2.y),
                f2bf((xv.z - mu) * rstd * gv2.z + bv2.z),
                f2bf((xv.w - mu) * rstd * gv2.w + bv2.w)};
  ((short4v*)(hfb + (size_t)row * 1024))[t] = pk;
}

// -------- 256x256 GEMM core, ONE barrier per K-tile, counted lgkm ----------
template <int EPI>
DEVI void gemm8_body(const short* __restrict__ A, const short* __restrict__ B,
                     int K, int kbase, int m0, int n0,
                     const float* __restrict__ f0, const float* __restrict__ f1,
                     const float* __restrict__ f2, short* __restrict__ s0,
                     short* __restrict__ s1, short* __restrict__ s2) {
  extern __shared__ __align__(16) char lds[];  // 131072 B
  constexpr int NT = 16;
  const int tid = threadIdx.x;
  const int l = tid & 63, w = tid >> 6;
  const int wrM = w >> 2, wcN = w & 3;
  const int lr = l & 15, lg = l >> 4;

  const int cswz = (((lr & 1) << 2) | lg) ^ (lr >> 1);
  const int laneoff = ((lr >> 1) << 7) + (cswz << 4);

  const int rsel = l >> 3;
  const int scz = (l & 7) ^ rsel;
  const int s_roff = w * 16 + rsel * 2 + (scz >> 2);
  const int s_kc = (scz & 3) * 8;
  const short* Asrc = A + (size_t)(m0 + s_roff) * K + kbase + s_kc;
  const short* Bsrc = B + (size_t)(n0 + s_roff) * K + kbase + s_kc;
  const size_t rstep = (size_t)128 * K;

  auto STAGE = [&](int op, int kh, int t) {
    const short* g = (op ? Bsrc : Asrc) + t * 64 + kh * 32;
    char* d = lds + ((t & 1) * 65536 + op * 32768 + kh * 16384 + w * 1024);
    gload_lds16(g, d);
    gload_lds16(g + rstep, d + 8192);
  };

  f32x4 acc[8][4] = {};

  // prologue: tile 0 all 4 units; full drain (one-time).
  STAGE(0, 0, 0); STAGE(1, 0, 0); STAGE(0, 1, 0); STAGE(1, 1, 0);
  vmwN<0>(); BAR(); SB0();

  for (int t = 0; t < NT; ++t) {
    const bool st = (t + 1) < NT;
    const char* pa0 = lds + (t & 1) * 65536 + wrM * 8192 + laneoff;
    const char* pb0 = lds + (t & 1) * 65536 + 32768 + wcN * 4096 + laneoff;
#pragma unroll
    for (int kh = 0; kh < 2; ++kh) {
      const char* pa = pa0 + kh * 16384;
      const char* pb = pb0 + kh * 16384;
      short8 a[8], b[4];
      // first 10 reads (a frags + b01), then SB0 pins the split so
      // lgkm(2) provably covers them; b23 float past the first wait.
#pragma unroll
      for (int mt = 0; mt < 8; ++mt) a[mt] = *(const short8*)(pa + mt * 1024);
      b[0] = *(const short8*)(pb);
      b[1] = *(const short8*)(pb + 1024);
      SB0();
      b[2] = *(const short8*)(pb + 2048);
      b[3] = *(const short8*)(pb + 3072);
      if (kh == 0 && st) {  // all 4 units of tile t+1 staged at tile start
        STAGE(0, 0, t + 1); STAGE(1, 0, t + 1);
        STAGE(0, 1, t + 1); STAGE(1, 1, t + 1);
      }
      lgkmN<2>();  // a[0..7], b01 retired; b23 may float
      __builtin_amdgcn_s_setprio(1);
#pragma unroll
      for (int mt = 0; mt < 8; ++mt) {
        acc[mt][0] = __builtin_amdgcn_mfma_f32_16x16x32_bf16(a[mt], b[0], acc[mt][0], 0, 0, 0);
        acc[mt][1] = __builtin_amdgcn_mfma_f32_16x16x32_bf16(a[mt], b[1], acc[mt][1], 0, 0, 0);
      }
      __builtin_amdgcn_s_setprio(0);
      lgkmN<0>();  // b23 retired
      __builtin_amdgcn_s_setprio(1);
#pragma unroll
      for (int mt = 0; mt < 8; ++mt) {
        acc[mt][2] = __builtin_amdgcn_mfma_f32_16x16x32_bf16(a[mt], b[2], acc[mt][2], 0, 0, 0);
        acc[mt][3] = __builtin_amdgcn_mfma_f32_16x16x32_bf16(a[mt], b[3], acc[mt][3], 0, 0, 0);
      }
      __builtin_amdgcn_s_setprio(0);
    }
    // tile end: drain stages (issued ~2500 cyc ago), then single sync.
    if (st) vmwN<0>();
    BAR(); SB0();
  }

  // --------------------------- epilogue ---------------------------
#pragma unroll
  for (int mt = 0; mt < 8; ++mt) {
#pragma unroll
    for (int nt = 0; nt < 4; ++nt) {
      const int col = n0 + wcN * 64 + nt * 16 + lr;
      const int row0 = m0 + wrM * 128 + mt * 16 + lg * 4;
      if constexpr (EPI == 0) {  // QKV scatter
        const int sel = col >> 10, nn = col & 1023;
        const int hh = nn >> 6, dd = nn & 63;
        const int bb = row0 >> 10, tt0 = row0 & 1023;
        if (sel == 2) {
          const float bias = f2[nn];
          short4v pk = {f2bf(acc[mt][nt][0] + bias), f2bf(acc[mt][nt][1] + bias),
                        f2bf(acc[mt][nt][2] + bias), f2bf(acc[mt][nt][3] + bias)};
          *(short4v*)&s2[(((size_t)(bb * 16 + hh)) * 64 + dd) * 1024 + tt0] = pk;
        } else {
          const float bias = (sel == 0) ? f0[nn] : f1[nn];
          short* dst = (sel == 0) ? s0 : s1;
#pragma unroll
          for (int r = 0; r < 4; ++r)
            dst[(((size_t)(bb * 16 + hh)) * 1024 + tt0 + r) * 64 + dd] =
                f2bf(acc[mt][nt][r] + bias);
        }
      } else if constexpr (EPI == 1) {  // FFN1 bias+relu -> bf16
#pragma unroll
        for (int r = 0; r < 4; ++r) {
          float val = fmaxf(acc[mt][nt][r] + f0[col], 0.0f);
          s0[(size_t)(row0 + r) * 4096 + col] = f2bf(val);
        }
      } else {  // split-K partials, bf16
#pragma unroll
        for (int r = 0; r < 4; ++r)
          s0[(size_t)(row0 + r) * 1024 + col] = f2bf(acc[mt][nt][r]);
      }
    }
  }
}

__global__ __launch_bounds__(512, 2) void gemm8_qkv(
    const short* __restrict__ A, const short* __restrict__ B,
    const float* __restrict__ bq, const float* __restrict__ bk,
    const float* __restrict__ bv, short* __restrict__ q,
    short* __restrict__ k, short* __restrict__ vt) {
  int bx, by;
  xcd_swz(12, 16, bx, by);
  gemm8_body<0>(A, B, 1024, 0, by * 256, bx * 256, bq, bk, bv, q, k, vt);
}

__global__ __launch_bounds__(512, 2) void gemm8_ffn1(
    const short* __restrict__ A, const short* __restrict__ B,
    const float* __restrict__ b1f, short* __restrict__ u) {
  int bx, by;
  xcd_swz(16, 16, bx, by);
  gemm8_body<1>(A, B, 1024, 0, by * 256, bx * 256, b1f, nullptr, nullptr, u,
                nullptr, nullptr);
}

// split-K x4: z in [0,4), K-chunk of 1024 over K=4096; writes bf16 partials.
__global__ __launch_bounds__(512, 2) void gemm8_ffn2sk(
    const short* __restrict__ A, const short* __restrict__ B,
    short* __restrict__ part) {
  const int z = blockIdx.z;
  int bx, by;
  xcd_swz(4, 16, bx, by);
  gemm8_body<2>(A, B, 4096, z * 1024, by * 256, bx * 256, nullptr, nullptr,
                nullptr, part + (size_t)z * 4096 * 1024, nullptr, nullptr);
}

// out = sum_z part[z] + b2f + hf + x3  (partials/hf/x3 bf16, out f32)
__global__ __launch_bounds__(256) void ffn2_reduce(
    const short* __restrict__ part, const float* __restrict__ b2f,
    const short* __restrict__ hfb, const short* __restrict__ x3,
    float* __restrict__ out) {
  const size_t i8 = (size_t)blockIdx.x * 256 + threadIdx.x;  // short8 index
  const size_t S = (size_t)4096 * 1024 / 8;
  short8 a0 = ((const short8*)part)[i8];
  short8 a1 = ((const short8*)part)[i8 + S];
  short8 a2 = ((const short8*)part)[i8 + 2 * S];
  short8 a3 = ((const short8*)part)[i8 + 3 * S];
  short8 xv = ((const short8*)x3)[i8];
  short8 hv = ((const short8*)hfb)[i8];
  const int cb = (int)((i8 * 2) & 255);
  float4 bb0 = ((const float4*)b2f)[cb];
  float4 bb1 = ((const float4*)b2f)[cb + 1];
  float ob[8];
#pragma unroll
  for (int j = 0; j < 8; ++j) {
    const float bbv = j < 4 ? ((const float*)&bb0)[j] : ((const float*)&bb1)[j - 4];
    ob[j] = bf2f(a0[j]) + bf2f(a1[j]) + bf2f(a2[j]) + bf2f(a3[j]) + bbv +
            bf2f(hv[j]) + bf2f(xv[j]);
  }
  float4 o0 = {ob[0], ob[1], ob[2], ob[3]};
  float4 o1 = {ob[4], ob[5], ob[6], ob[7]};
  ((float4*)out)[i8 * 2] = o0;
  ((float4*)out)[i8 * 2 + 1] = o1;
}

// ----------------------------- flash attention -----------------------------
__global__ __launch_bounds__(256, 5) void attn_kernel(
    const short* __restrict__ q, const short* __restrict__ k,
    const short* __restrict__ vt, short* __restrict__ o) {
  __shared__ __align__(16) short Ksm[64 * 64];
  __shared__ __align__(16) short Vsm[64 * 64];
  __shared__ __align__(16) short Psm[4 * 16 * 64];
  const int bh = blockIdx.x;
  const int qt = 15 - blockIdx.y;  // heavy blocks dispatch FIRST
  const int tid = threadIdx.x, lane = tid & 63, w = tid >> 6;
  const int lr = lane & 15, lg = lane >> 4;

  const short* qb = q + (size_t)bh * 1024 * 64;
  const short* kb = k + (size_t)bh * 1024 * 64;
  const short* vb = vt + (size_t)bh * 64 * 1024;

  const int qrow = qt * 64 + w * 16 + lr;
  short8 qf0 = *(const short8*)&qb[(size_t)qrow * 64 + lg * 8];
  short8 qf1 = *(const short8*)&qb[(size_t)qrow * 64 + 32 + lg * 8];

  f32x4 oacc[4] = {};
  float mrun = -1e30f, lrun = 0.0f;

  const float scale2 = 0.03125f * 1.44269504088896f;  // (1/sqrt(C))*log2(e)
  const int srow = tid >> 3;
  const int sc8 = tid & 7;
  char* pw = (char*)(Psm + w * 1024);
  const int qloc = w * 16 + lr;
  const int rowswz = (lr & 7) << 4;

  short8 kreg[2], vreg[2];
#pragma unroll
  for (int p = 0; p < 2; ++p) {
    const int rr = srow + p * 32;
    kreg[p] = *(const short8*)&kb[(size_t)rr * 64 + sc8 * 8];
    vreg[p] = *(const short8*)&vb[(size_t)rr * 1024 + sc8 * 8];
  }

  for (int kt = 0; kt <= qt; ++kt) {
#pragma unroll
    for (int p = 0; p < 2; ++p) {
      const int rr = srow + p * 32;
      *(short8*)((char*)Ksm + rr * 128 + ((sc8 ^ (rr & 7)) << 4)) = kreg[p];
      *(short8*)((char*)Vsm + rr * 128 + ((sc8 ^ (rr & 7)) << 4)) = vreg[p];
    }
    __syncthreads();
    if (kt < qt) {
#pragma unroll
      for (int p = 0; p < 2; ++p) {
        const int rr = srow + p * 32;
        kreg[p] =
            *(const short8*)&kb[((size_t)((kt + 1) * 64 + rr)) * 64 + sc8 * 8];
        vreg[p] =
            *(const short8*)&vb[(size_t)rr * 1024 + (kt + 1) * 64 + sc8 * 8];
      }
    }

    f32x4 sfr[4];
#pragma unroll
    for (int nt = 0; nt < 4; ++nt) {
      const int krow = nt * 16 + lr;
      short8 kf0 = *(const short8*)((const char*)Ksm + krow * 128 +
                                    (((0 + lg) ^ (krow & 7)) << 4));
      short8 kf1 = *(const short8*)((const char*)Ksm + krow * 128 +
                                    (((4 + lg) ^ (krow & 7)) << 4));
      f32x4 z = {};
      z = __builtin_amdgcn_mfma_f32_16x16x32_bf16(kf0, qf0, z, 0, 0, 0);
      z = __builtin_amdgcn_mfma_f32_16x16x32_bf16(kf1, qf1, z, 0, 0, 0);
      sfr[nt] = z;
    }
    if (kt == qt) {
#pragma unroll
      for (int nt = 0; nt < 4; ++nt) {
        const int kb0 = nt * 16 + lg * 4;
#pragma unroll
        for (int r = 0; r < 4; ++r)
          sfr[nt][r] = (kb0 + r <= qloc) ? sfr[nt][r] * scale2 : -1e30f;
      }
    } else {
#pragma unroll
      for (int nt = 0; nt < 4; ++nt)
#pragma unroll
        for (int r = 0; r < 4; ++r) sfr[nt][r] *= scale2;
    }
    float pm;
    {
      float a0 = fmaxf(fmaxf(sfr[0][0], sfr[0][1]), fmaxf(sfr[0][2], sfr[0][3]));
      float a1 = fmaxf(fmaxf(sfr[1][0], sfr[1][1]), fmaxf(sfr[1][2], sfr[1][3]));
      float a2 = fmaxf(fmaxf(sfr[2][0], sfr[2][1]), fmaxf(sfr[2][2], sfr[2][3]));
      float a3 = fmaxf(fmaxf(sfr[3][0], sfr[3][1]), fmaxf(sfr[3][2], sfr[3][3]));
      pm = fmaxf(fmaxf(a0, a1), fmaxf(a2, a3));
      pm = fmaxf(pm, __shfl_xor(pm, 16, 64));
      pm = fmaxf(pm, __shfl_xor(pm, 32, 64));
    }
    if (!__all(pm - mrun <= 8.0f)) {
      const float mnew = fmaxf(mrun, pm);
      const float alpha = exp2f(mrun - mnew);
      mrun = mnew;
      lrun *= alpha;
#pragma unroll
      for (int nt = 0; nt < 4; ++nt)
#pragma unroll
        for (int r = 0; r < 4; ++r) oacc[nt][r] *= alpha;
    }
    float rs;
    {
#pragma unroll
      for (int nt = 0; nt < 4; ++nt)
#pragma unroll
        for (int r = 0; r < 4; ++r) sfr[nt][r] = exp2f(sfr[nt][r] - mrun);
      float s0 = (sfr[0][0] + sfr[0][1]) + (sfr[0][2] + sfr[0][3]);
      float s1 = (sfr[1][0] + sfr[1][1]) + (sfr[1][2] + sfr[1][3]);
      float s2 = (sfr[2][0] + sfr[2][1]) + (sfr[2][2] + sfr[2][3]);
      float s3 = (sfr[3][0] + sfr[3][1]) + (sfr[3][2] + sfr[3][3]);
      rs = (s0 + s1) + (s2 + s3);
      rs += __shfl_xor(rs, 16, 64);
      rs += __shfl_xor(rs, 32, 64);
    }
    lrun += rs;

#pragma unroll
    for (int nt = 0; nt < 4; ++nt) {
      unsigned w0, w1;
      asm("v_cvt_pk_bf16_f32 %0, %1, %2"
          : "=v"(w0) : "v"(sfr[nt][0]), "v"(sfr[nt][1]));
      asm("v_cvt_pk_bf16_f32 %0, %1, %2"
          : "=v"(w1) : "v"(sfr[nt][2]), "v"(sfr[nt][3]));
      uint2 pk2 = {w0, w1};
      *(uint2*)(pw + lr * 128 + ((nt * 32 + lg * 8) ^ rowswz)) = pk2;
    }

#pragma unroll
    for (int kc = 0; kc < 2; ++kc) {
      short8 pb8 = *(const short8*)(pw + lr * 128 + ((kc * 64 + lg * 16) ^ rowswz));
#pragma unroll
      for (int nt = 0; nt < 4; ++nt) {
        const int vrow = nt * 16 + lr;
        short8 vf = *(const short8*)((const char*)Vsm + vrow * 128 +
                                     (((kc * 4 + lg) ^ (vrow & 7)) << 4));
        oacc[nt] = __builtin_amdgcn_mfma_f32_16x16x32_bf16(vf, pb8, oacc[nt], 0, 0, 0);
      }
    }
    __syncthreads();
  }

  const float inv = 1.0f / lrun;
  short* ob = o + (size_t)(bh >> 4) * 1024 * 1024 +
              (size_t)(qt * 64 + qloc) * 1024 + (bh & 15) * 64;
#pragma unroll
  for (int nt = 0; nt < 4; ++nt) {
    short4v pk = {f2bf(oacc[nt][0] * inv), f2bf(oacc[nt][1] * inv),
                  f2bf(oacc[nt][2] * inv), f2bf(oacc[nt][3] * inv)};
    *(short4v*)&ob[nt * 16 + lg * 4] = pk;
  }
}

// ------------------------------- launcher ----------------------------------
extern "C" void kernel_launch(void* const* d_in, const int* in_sizes, int n_in,
                              void* d_out, int out_size, void* d_ws,
                              size_t ws_size, hipStream_t stream) {
  const float* x = (const float*)d_in[0];
  const float* Wq = (const float*)d_in[1];
  const float* bq = (const float*)d_in[2];
  const float* Wk = (const float*)d_in[3];
  const float* bk = (const float*)d_in[4];
  const float* Wv = (const float*)d_in[5];
  const float* bv = (const float*)d_in[6];
  const float* g1 = (const float*)d_in[7];
  const float* b1 = (const float*)d_in[8];
  const float* g2 = (const float*)d_in[9];
  const float* b2 = (const float*)d_in[10];
  const float* gf = (const float*)d_in[11];
  const float* bfp = (const float*)d_in[12];
  const float* W1 = (const float*)d_in[13];
  const float* b1f = (const float*)d_in[14];
  const float* W2 = (const float*)d_in[15];
  const float* b2f = (const float*)d_in[16];
  float* out = (float*)d_out;

  (void)hipFuncSetAttribute((const void*)gemm8_qkv,
                            hipFuncAttributeMaxDynamicSharedMemorySize, 131072);
  (void)hipFuncSetAttribute((const void*)gemm8_ffn1,
                            hipFuncAttributeMaxDynamicSharedMemorySize, 131072);
  (void)hipFuncSetAttribute((const void*)gemm8_ffn2sk,
                            hipFuncAttributeMaxDynamicSharedMemorySize, 131072);

  const size_t MB = 1024 * 1024;
  char* p = (char*)d_ws;
  // Region A (48MB): all dead before gemm8_ffn2sk; 32MB bf16 partials alias.
  short* qbuf = (short*)(p + 0 * MB);      // 8MB  dead after attn
  short* kbuf = (short*)(p + 8 * MB);      // 8MB  dead after attn
  short* vtb = (short*)(p + 16 * MB);      // 8MB  dead after attn
  short* obuf = (short*)(p + 24 * MB);     // 8MB  bf16 O, dead after ln2f
  short* wqkv_t = (short*)(p + 32 * MB);   // 6MB  dead after gemm8_qkv
  short* w1_t = (short*)(p + 40 * MB);     // 8MB  dead after gemm8_ffn1
  short* part = (short*)(p + 0 * MB);      // 32MB bf16 partials (alias)
  // Region B (64MB): live through the end.
  char* q = p + 48 * MB;
  short* w2_t = (short*)(q + 0 * MB);      // 8MB
  short* hbb = (short*)(q + 8 * MB);       // 8MB
  short* x3b = (short*)(q + 16 * MB);      // 8MB bf16
  short* hfb = (short*)(q + 24 * MB);      // 8MB
  short* ub = (short*)(q + 32 * MB);       // 32MB

  transpose_all<<<11264, dim3(32, 8), 0, stream>>>(Wq, Wk, Wv, W1, W2, wqkv_t,
                                                   w1_t, w2_t);

  ln1_kernel<<<4096, 256, 0, stream>>>(x, g1, b1, hbb);

  gemm8_qkv<<<dim3(12, 16), 512, 131072, stream>>>(hbb, wqkv_t, bq, bk, bv,
                                                   qbuf, kbuf, vtb);

  attn_kernel<<<dim3(64, 16), 256, 0, stream>>>(qbuf, kbuf, vtb, obuf);

  ln2f_kernel<<<4096, 256, 0, stream>>>(hbb, obuf, g2, b2, gf, bfp, x3b, hfb);

  gemm8_ffn1<<<dim3(16, 16), 512, 131072, stream>>>(hfb, w1_t, b1f, ub);

  gemm8_ffn2sk<<<dim3(4, 16, 4), 512, 131072, stream>>>(ub, w2_t, part);

  ffn2_reduce<<<2048, 256, 0, stream>>>(part, b2f, hfb, x3b, out);
}